// Round 7
// baseline (428.770 us; speedup 1.0000x reference)
//
#include <hip/hip_runtime.h>
#include <hip/hip_fp16.h>

#define RES 256
#define MS 256
#define ST 512
#define NB 32
#define LUTLEN 262144
#define LUTW 8192      // LUTLEN/32
#define NOUT 32
#define NBLK 256       // 1 sample per block

typedef __attribute__((ext_vector_type(8))) _Float16 half8;
typedef __attribute__((ext_vector_type(4))) float f32x4;

// lgkm-only publish barrier: drain own LDS ops, raw barrier (no vmcnt drain).
__device__ __forceinline__ void publish_barrier() {
    asm volatile("s_waitcnt lgkmcnt(0)" ::: "memory");
    __builtin_amdgcn_s_barrier();
}

// ---- per-node reachable-size + exclusive prefix sum (1 block, 256 thr) ----
__global__ __launch_bounds__(256) void lut_offsets_kernel(const int* __restrict__ W,
                                                          const int* __restrict__ primes,
                                                          int* __restrict__ off) {
    __shared__ int s[RES];
    const int n = threadIdx.x;
    int maxsum = 0;
    for (int k = 0; k < RES; ++k)
        maxsum += (W[n * RES + k] != 0) ? primes[k] : 0;
    int nw = (maxsum >> 5) + 1;
    s[n] = nw;
    __syncthreads();
    for (int d = 1; d < RES; d <<= 1) {
        int v = (n >= d) ? s[n - d] : 0;
        __syncthreads();
        s[n] += v;
        __syncthreads();
    }
    off[n] = s[n] - nw;
    if (n == RES - 1) off[RES] = s[n];
}

// ---- compact bit-pack: block b = node b, words 0..nw-1 ----
__global__ __launch_bounds__(512) void pack_lut2_kernel(const int* __restrict__ lut,
                                                        const int* __restrict__ off,
                                                        unsigned* __restrict__ lutp) {
    const int n = blockIdx.x;
    const int o = off[n];
    const int nw = off[n + 1] - o;
    const int* src = lut + (size_t)n * LUTLEN;
    for (int w = threadIdx.x; w < nw; w += blockDim.x) {
        const int4* p = (const int4*)(src + (size_t)w * 32);
        unsigned word = 0u;
#pragma unroll
        for (int c = 0; c < 8; ++c) {
            const int4 v = p[c];
            word |= (v.x != 0 ? 1u : 0u) << (4 * c + 0);
            word |= (v.y != 0 ? 1u : 0u) << (4 * c + 1);
            word |= (v.z != 0 ? 1u : 0u) << (4 * c + 2);
            word |= (v.w != 0 ? 1u : 0u) << (4 * c + 3);
        }
        lutp[o + w] = word;
    }
}

// Pack x time-major: xp[t*MS + m] = 32 input bits of (m, t).
__global__ __launch_bounds__(256) void pack_x_kernel(const int* __restrict__ x,
                                                     unsigned* __restrict__ xp) {
    const int total = MS * ST;
    int w = blockIdx.x * blockDim.x + threadIdx.x;
    const int stride = gridDim.x * blockDim.x;
    for (; w < total; w += stride) {
        const int4* p = (const int4*)(x + (size_t)w * 32);
        unsigned word = 0u;
#pragma unroll
        for (int c = 0; c < 8; ++c) {
            const int4 v = p[c];
            word |= (v.x != 0 ? 1u : 0u) << (4 * c + 0);
            word |= (v.y != 0 ? 1u : 0u) << (4 * c + 1);
            word |= (v.z != 0 ? 1u : 0u) << (4 * c + 2);
            word |= (v.w != 0 ? 1u : 0u) << (4 * c + 3);
        }
        const int m = w >> 9;
        const int t = w & (ST - 1);
        xp[t * MS + m] = word;
    }
}

// 256 blocks x 256 threads (4 waves); block = 1 sample. Each wave owns 64 nodes
// (4 B-tiles of 16). Broadcast-row A => all C rows identical, so lane = tau*16+r
// holds tile tau's col r: every lane owns node wid*64+lane -> ONE 64-lane gather
// + ONE contiguous 128B ds_write per wave. 32 MFMA/wave as 8 indep chains.
template<bool LP, bool XP>
__global__ __launch_bounds__(256, 1) void reservoir_kernel(
    const int* __restrict__ xraw,
    const unsigned* __restrict__ xp,
    const int* __restrict__ lutraw,
    const unsigned* __restrict__ lutp,
    const int* __restrict__ off,
    const int* __restrict__ init_res,
    const int* __restrict__ W,
    const int* __restrict__ primes,
    const int* __restrict__ input_nodes,
    const float* __restrict__ rw,
    const float* __restrict__ rb,
    float* __restrict__ out)
{
    __shared__ __align__(16) _Float16 vArow[2][264];  // double-buffered state row
    __shared__ unsigned xw_lds[ST];                   // this sample's 512 x-words

    const int tid = threadIdx.x;
    const int lane = tid & 63;
    const int wid = tid >> 6;        // 0..3, wave owns nodes wid*64..wid*64+63
    const int g = lane >> 4;         // 0..3 (k-group)
    const int r = lane & 15;         // B col within tile
    const int m0 = blockIdx.x;       // the sample

    const int nn = wid * 64 + lane;  // this lane's node (all 64 lanes own one)

    const _Float16 pz = (_Float16)(float)primes[nn];
    const _Float16 z  = (_Float16)0.0f;

    const unsigned* lpn = LP ? (lutp + off[nn]) : nullptr;
    int jn = -1;
    for (int j = 0; j < NB; ++j)
        if (input_nodes[j] == nn) jn = j;

    // B fragments: 4 tiles x 8 kc, B[k][col] = W[node col][k], 0/1 f16. 128 VGPRs.
    half8 B[4][8];
#pragma unroll
    for (int tau = 0; tau < 4; ++tau) {
        const int nc = wid * 64 + tau * 16 + r;   // this lane's B col node
#pragma unroll
        for (int kc = 0; kc < 8; ++kc) {
            const int kb = kc * 32 + g * 8;
            const int4* wp = (const int4*)(W + nc * RES + kb);
            const int4 wa = wp[0], wb = wp[1];
            half8 b;
            b[0] = wa.x != 0 ? (_Float16)1.0f : z;  b[1] = wa.y != 0 ? (_Float16)1.0f : z;
            b[2] = wa.z != 0 ? (_Float16)1.0f : z;  b[3] = wa.w != 0 ? (_Float16)1.0f : z;
            b[4] = wb.x != 0 ? (_Float16)1.0f : z;  b[5] = wb.y != 0 ? (_Float16)1.0f : z;
            b[6] = wb.z != 0 ? (_Float16)1.0f : z;  b[7] = wb.w != 0 ? (_Float16)1.0f : z;
            B[tau][kc] = b;
        }
    }

    // stage this sample's x words into LDS (256 threads x 2 rounds)
    if (XP) {
        xw_lds[tid] = xp[tid * MS + m0];
        xw_lds[tid + 256] = xp[(tid + 256) * MS + m0];
    }

    // init: S(0) = init_res with step-0 scatter (every lane owns one node)
    {
        int b;
        if (XP) {
            const unsigned x0 = xp[m0];
            b = (jn >= 0) ? (int)((x0 >> jn) & 1u) : (init_res[nn] != 0);
        } else {
            b = (jn >= 0) ? (xraw[(m0 * ST) * NB + jn] != 0) : (init_res[nn] != 0);
        }
        vArow[0][nn] = b ? pz : z;
    }
    __syncthreads();

    auto STEP = [&](int cur, int nxt, int t) {
        unsigned xa = 0u;
        if (XP) xa = xw_lds[(t + 1) & (ST - 1)];   // wraps at last step; unused then
        half8 A[8];
#pragma unroll
        for (int kc = 0; kc < 8; ++kc)
            A[kc] = *(const half8*)&vArow[cur][kc * 32 + g * 8];  // broadcast read
        f32x4 ca[4], cb[4];
#pragma unroll
        for (int tau = 0; tau < 4; ++tau) { ca[tau] = {0.f,0.f,0.f,0.f}; cb[tau] = {0.f,0.f,0.f,0.f}; }
        // 32 MFMA as 8 independent chains (4 tiles x 2 parity, depth 4)
#pragma unroll
        for (int kc = 0; kc < 8; kc += 2) {
#pragma unroll
            for (int tau = 0; tau < 4; ++tau) {
                ca[tau] = __builtin_amdgcn_mfma_f32_16x16x32_f16(A[kc],   B[tau][kc],   ca[tau], 0, 0, 0);
                cb[tau] = __builtin_amdgcn_mfma_f32_16x16x32_f16(A[kc+1], B[tau][kc+1], cb[tau], 0, 0, 0);
            }
        }
        // own node's sum: tile index = g (nn = wid*64 + g*16 + r), rows identical
        float f0 = ca[0][0] + cb[0][0];
        float f1 = ca[1][0] + cb[1][0];
        float f2 = ca[2][0] + cb[2][0];
        float f3 = ca[3][0] + cb[3][0];
        float f = (g == 0) ? f0 : (g == 1) ? f1 : (g == 2) ? f2 : f3;
        const unsigned i = (unsigned)f;
        int b;
        if (LP) {
            const unsigned w = lpn[i >> 5];
            b = (int)((w >> (i & 31u)) & 1u);
        } else {
            b = (lutraw[(size_t)nn * LUTLEN + i] != 0);
        }
        if (t != ST - 1 && jn >= 0) {
            b = XP ? (int)((xa >> jn) & 1u)
                   : (xraw[(m0 * ST + t + 1) * NB + jn] != 0);
        }
        vArow[nxt][nn] = b ? pz : z;   // contiguous 2B x 64 lanes = 128B/wave
        publish_barrier();
    };

#pragma unroll 1
    for (int tt = 0; tt < ST; tt += 2) {
        STEP(0, 1, tt);
        STEP(1, 0, tt + 1);
    }

    // readout: final state S(512) in buf 0
    if (tid < NOUT) {
        const int o = tid;
        float acc = rb[o];
        for (int n = 0; n < RES; ++n) {
            if (vArow[0][n] != z) acc += rw[o * RES + n];
        }
        out[m0 * NOUT + o] = acc;
    }
}

extern "C" void kernel_launch(void* const* d_in, const int* in_sizes, int n_in,
                              void* d_out, int out_size, void* d_ws, size_t ws_size,
                              hipStream_t stream) {
    const int* x           = (const int*)d_in[0];
    const int* lut         = (const int*)d_in[1];
    const int* init_res    = (const int*)d_in[2];
    const int* W           = (const int*)d_in[3];
    const int* primes      = (const int*)d_in[4];
    const int* input_nodes = (const int*)d_in[5];
    const float* rw        = (const float*)d_in[6];
    const float* rb        = (const float*)d_in[7];
    float* out = (float*)d_out;

    const size_t lutp_bytes = (size_t)RES * LUTW * sizeof(unsigned); // 8 MB cap
    const size_t xp_bytes   = (size_t)ST * MS * sizeof(unsigned);    // 512 KB
    const size_t off_bytes  = (RES + 1) * sizeof(int);

    unsigned* lutp = nullptr;
    unsigned* xp = nullptr;
    int* off = nullptr;
    bool use_lp = false, use_xp = false;
    unsigned char* ws = (unsigned char*)d_ws;
    if (ws_size >= lutp_bytes + xp_bytes + 256 + off_bytes) {
        lutp = (unsigned*)ws;
        xp = (unsigned*)(ws + lutp_bytes);
        off = (int*)(ws + lutp_bytes + xp_bytes);
        use_lp = use_xp = true;
    } else if (ws_size >= xp_bytes) {
        xp = (unsigned*)ws;
        use_xp = true;
    }

    if (use_lp) {
        hipLaunchKernelGGL(lut_offsets_kernel, dim3(1), dim3(256), 0, stream, W, primes, off);
        hipLaunchKernelGGL(pack_lut2_kernel, dim3(RES), dim3(512), 0, stream, lut, off, lutp);
    }
    if (use_xp) hipLaunchKernelGGL(pack_x_kernel, dim3(512), dim3(256), 0, stream, x, xp);

    if (use_lp)
        hipLaunchKernelGGL((reservoir_kernel<true, true>), dim3(NBLK), dim3(256), 0, stream,
                           x, xp, lut, lutp, off, init_res, W, primes, input_nodes, rw, rb, out);
    else if (use_xp)
        hipLaunchKernelGGL((reservoir_kernel<false, true>), dim3(NBLK), dim3(256), 0, stream,
                           x, xp, lut, lutp, off, init_res, W, primes, input_nodes, rw, rb, out);
    else
        hipLaunchKernelGGL((reservoir_kernel<false, false>), dim3(NBLK), dim3(256), 0, stream,
                           x, xp, lut, lutp, off, init_res, W, primes, input_nodes, rw, rb, out);
}

// Round 8
// 389.968 us; speedup vs baseline: 1.0995x; 1.0995x over previous
//
#include <hip/hip_runtime.h>
#include <hip/hip_fp16.h>

#define RES 256
#define MS 256
#define ST 512
#define NB 32
#define LUTLEN 262144
#define LUTW 8192      // LUTLEN/32
#define NOUT 32
#define NBLK 256       // 1 sample per block

typedef __attribute__((ext_vector_type(8))) _Float16 half8;
typedef __attribute__((ext_vector_type(4))) float f32x4;

// lgkm-only publish barrier: drain own LDS ops, raw barrier (no vmcnt drain).
__device__ __forceinline__ void publish_barrier() {
    asm volatile("s_waitcnt lgkmcnt(0)" ::: "memory");
    __builtin_amdgcn_s_barrier();
}

// ---- per-node reachable-size + exclusive prefix sum (1 block, 256 thr) ----
__global__ __launch_bounds__(256) void lut_offsets_kernel(const int* __restrict__ W,
                                                          const int* __restrict__ primes,
                                                          int* __restrict__ off) {
    __shared__ int s[RES];
    const int n = threadIdx.x;
    int maxsum = 0;
    for (int k = 0; k < RES; ++k)
        maxsum += (W[n * RES + k] != 0) ? primes[k] : 0;
    int nw = (maxsum >> 5) + 1;
    s[n] = nw;
    __syncthreads();
    for (int d = 1; d < RES; d <<= 1) {
        int v = (n >= d) ? s[n - d] : 0;
        __syncthreads();
        s[n] += v;
        __syncthreads();
    }
    off[n] = s[n] - nw;
    if (n == RES - 1) off[RES] = s[n];
}

// ---- compact bit-pack: block b = node b, words 0..nw-1 ----
__global__ __launch_bounds__(512) void pack_lut2_kernel(const int* __restrict__ lut,
                                                        const int* __restrict__ off,
                                                        unsigned* __restrict__ lutp) {
    const int n = blockIdx.x;
    const int o = off[n];
    const int nw = off[n + 1] - o;
    const int* src = lut + (size_t)n * LUTLEN;
    for (int w = threadIdx.x; w < nw; w += blockDim.x) {
        const int4* p = (const int4*)(src + (size_t)w * 32);
        unsigned word = 0u;
#pragma unroll
        for (int c = 0; c < 8; ++c) {
            const int4 v = p[c];
            word |= (v.x != 0 ? 1u : 0u) << (4 * c + 0);
            word |= (v.y != 0 ? 1u : 0u) << (4 * c + 1);
            word |= (v.z != 0 ? 1u : 0u) << (4 * c + 2);
            word |= (v.w != 0 ? 1u : 0u) << (4 * c + 3);
        }
        lutp[o + w] = word;
    }
}

// Pack x time-major: xp[t*MS + m] = 32 input bits of (m, t).
__global__ __launch_bounds__(256) void pack_x_kernel(const int* __restrict__ x,
                                                     unsigned* __restrict__ xp) {
    const int total = MS * ST;
    int w = blockIdx.x * blockDim.x + threadIdx.x;
    const int stride = gridDim.x * blockDim.x;
    for (; w < total; w += stride) {
        const int4* p = (const int4*)(x + (size_t)w * 32);
        unsigned word = 0u;
#pragma unroll
        for (int c = 0; c < 8; ++c) {
            const int4 v = p[c];
            word |= (v.x != 0 ? 1u : 0u) << (4 * c + 0);
            word |= (v.y != 0 ? 1u : 0u) << (4 * c + 1);
            word |= (v.z != 0 ? 1u : 0u) << (4 * c + 2);
            word |= (v.w != 0 ? 1u : 0u) << (4 * c + 3);
        }
        const int m = w >> 9;
        const int t = w & (ST - 1);
        xp[t * MS + m] = word;
    }
}

// 256 blocks x 1024 threads (16 waves); block = 1 sample. Each wave owns 16 nodes
// (one B tile). Broadcast-row A => all C rows identical; lane r (g==0) owns node
// wid*16+r. Per wave per step: 8 ds_read_b128 + 8 MFMA (4 indep depth-2 chains) +
// one 16-lane gather + 32B contiguous write. 4 waves/SIMD for stall overlap.
template<bool LP, bool XP>
__global__ __launch_bounds__(1024, 1) void reservoir_kernel(
    const int* __restrict__ xraw,
    const unsigned* __restrict__ xp,
    const int* __restrict__ lutraw,
    const unsigned* __restrict__ lutp,
    const int* __restrict__ off,
    const int* __restrict__ init_res,
    const int* __restrict__ W,
    const int* __restrict__ primes,
    const int* __restrict__ input_nodes,
    const float* __restrict__ rw,
    const float* __restrict__ rb,
    float* __restrict__ out)
{
    __shared__ __align__(16) _Float16 vArow[2][264];  // double-buffered state row
    __shared__ unsigned xw_lds[ST];                   // this sample's 512 x-words

    const int tid = threadIdx.x;
    const int lane = tid & 63;
    const int wid = tid >> 6;        // 0..15, wave owns nodes wid*16..wid*16+15
    const int g = lane >> 4;         // 0..3 (k-group)
    const int r = lane & 15;         // B col within the wave's tile
    const int m0 = blockIdx.x;       // the sample

    const int nn = wid * 16 + r;     // own node (owned by g==0 lanes)
    const bool own = (g == 0);

    const _Float16 pz = (_Float16)(float)primes[nn];
    const _Float16 z  = (_Float16)0.0f;

    const unsigned* lpn = LP ? (lutp + off[nn]) : nullptr;
    int jn = -1;
    for (int j = 0; j < NB; ++j)
        if (input_nodes[j] == nn) jn = j;

    // B fragments: one tile x 8 kc, B[k][col r] = W[nn][k], 0/1 f16. 32 VGPRs.
    half8 B[8];
#pragma unroll
    for (int kc = 0; kc < 8; ++kc) {
        const int kb = kc * 32 + g * 8;
        const int4* wp = (const int4*)(W + nn * RES + kb);
        const int4 wa = wp[0], wb = wp[1];
        half8 b;
        b[0] = wa.x != 0 ? (_Float16)1.0f : z;  b[1] = wa.y != 0 ? (_Float16)1.0f : z;
        b[2] = wa.z != 0 ? (_Float16)1.0f : z;  b[3] = wa.w != 0 ? (_Float16)1.0f : z;
        b[4] = wb.x != 0 ? (_Float16)1.0f : z;  b[5] = wb.y != 0 ? (_Float16)1.0f : z;
        b[6] = wb.z != 0 ? (_Float16)1.0f : z;  b[7] = wb.w != 0 ? (_Float16)1.0f : z;
        B[kc] = b;
    }

    // stage this sample's x words into LDS (first 512 of 1024 threads)
    if (XP && tid < ST) xw_lds[tid] = xp[tid * MS + m0];

    // init: S(0) = init_res with step-0 scatter (g==0 lanes cover all 256 nodes)
    if (own) {
        int b;
        if (XP) {
            const unsigned x0 = xp[m0];
            b = (jn >= 0) ? (int)((x0 >> jn) & 1u) : (init_res[nn] != 0);
        } else {
            b = (jn >= 0) ? (xraw[(m0 * ST) * NB + jn] != 0) : (init_res[nn] != 0);
        }
        vArow[0][nn] = b ? pz : z;
    }
    __syncthreads();

    auto STEP = [&](int cur, int nxt, int t) {
        unsigned xa = 0u;
        if (XP) xa = xw_lds[(t + 1) & (ST - 1)];   // wraps at last step; unused then
        half8 A[8];
#pragma unroll
        for (int kc = 0; kc < 8; ++kc)
            A[kc] = *(const half8*)&vArow[cur][kc * 32 + g * 8];  // broadcast read
        f32x4 c0 = {0.f,0.f,0.f,0.f}, c1 = {0.f,0.f,0.f,0.f};
        f32x4 c2 = {0.f,0.f,0.f,0.f}, c3 = {0.f,0.f,0.f,0.f};
        // 8 MFMA as 4 independent depth-2 chains (disjoint kc, exact int sums)
        c0 = __builtin_amdgcn_mfma_f32_16x16x32_f16(A[0], B[0], c0, 0, 0, 0);
        c1 = __builtin_amdgcn_mfma_f32_16x16x32_f16(A[1], B[1], c1, 0, 0, 0);
        c2 = __builtin_amdgcn_mfma_f32_16x16x32_f16(A[2], B[2], c2, 0, 0, 0);
        c3 = __builtin_amdgcn_mfma_f32_16x16x32_f16(A[3], B[3], c3, 0, 0, 0);
        c0 = __builtin_amdgcn_mfma_f32_16x16x32_f16(A[4], B[4], c0, 0, 0, 0);
        c1 = __builtin_amdgcn_mfma_f32_16x16x32_f16(A[5], B[5], c1, 0, 0, 0);
        c2 = __builtin_amdgcn_mfma_f32_16x16x32_f16(A[6], B[6], c2, 0, 0, 0);
        c3 = __builtin_amdgcn_mfma_f32_16x16x32_f16(A[7], B[7], c3, 0, 0, 0);

        if (own) {
            const float f = (c0[0] + c1[0]) + (c2[0] + c3[0]);
            const unsigned i = (unsigned)f;
            int b;
            if (LP) {
                const unsigned w = lpn[i >> 5];
                b = (int)((w >> (i & 31u)) & 1u);
            } else {
                b = (lutraw[(size_t)nn * LUTLEN + i] != 0);
            }
            if (t != ST - 1 && jn >= 0) {
                b = XP ? (int)((xa >> jn) & 1u)
                       : (xraw[(m0 * ST + t + 1) * NB + jn] != 0);
            }
            vArow[nxt][nn] = b ? pz : z;   // contiguous 2B x 16 lanes = 32B/wave
        }
        publish_barrier();
    };

#pragma unroll 1
    for (int tt = 0; tt < ST; tt += 2) {
        STEP(0, 1, tt);
        STEP(1, 0, tt + 1);
    }

    // readout: final state S(512) in buf 0
    if (tid < NOUT) {
        const int o = tid;
        float acc = rb[o];
        for (int n = 0; n < RES; ++n) {
            if (vArow[0][n] != z) acc += rw[o * RES + n];
        }
        out[m0 * NOUT + o] = acc;
    }
}

extern "C" void kernel_launch(void* const* d_in, const int* in_sizes, int n_in,
                              void* d_out, int out_size, void* d_ws, size_t ws_size,
                              hipStream_t stream) {
    const int* x           = (const int*)d_in[0];
    const int* lut         = (const int*)d_in[1];
    const int* init_res    = (const int*)d_in[2];
    const int* W           = (const int*)d_in[3];
    const int* primes      = (const int*)d_in[4];
    const int* input_nodes = (const int*)d_in[5];
    const float* rw        = (const float*)d_in[6];
    const float* rb        = (const float*)d_in[7];
    float* out = (float*)d_out;

    const size_t lutp_bytes = (size_t)RES * LUTW * sizeof(unsigned); // 8 MB cap
    const size_t xp_bytes   = (size_t)ST * MS * sizeof(unsigned);    // 512 KB
    const size_t off_bytes  = (RES + 1) * sizeof(int);

    unsigned* lutp = nullptr;
    unsigned* xp = nullptr;
    int* off = nullptr;
    bool use_lp = false, use_xp = false;
    unsigned char* ws = (unsigned char*)d_ws;
    if (ws_size >= lutp_bytes + xp_bytes + 256 + off_bytes) {
        lutp = (unsigned*)ws;
        xp = (unsigned*)(ws + lutp_bytes);
        off = (int*)(ws + lutp_bytes + xp_bytes);
        use_lp = use_xp = true;
    } else if (ws_size >= xp_bytes) {
        xp = (unsigned*)ws;
        use_xp = true;
    }

    if (use_lp) {
        hipLaunchKernelGGL(lut_offsets_kernel, dim3(1), dim3(256), 0, stream, W, primes, off);
        hipLaunchKernelGGL(pack_lut2_kernel, dim3(RES), dim3(512), 0, stream, lut, off, lutp);
    }
    if (use_xp) hipLaunchKernelGGL(pack_x_kernel, dim3(512), dim3(256), 0, stream, x, xp);

    if (use_lp)
        hipLaunchKernelGGL((reservoir_kernel<true, true>), dim3(NBLK), dim3(1024), 0, stream,
                           x, xp, lut, lutp, off, init_res, W, primes, input_nodes, rw, rb, out);
    else if (use_xp)
        hipLaunchKernelGGL((reservoir_kernel<false, true>), dim3(NBLK), dim3(1024), 0, stream,
                           x, xp, lut, lutp, off, init_res, W, primes, input_nodes, rw, rb, out);
    else
        hipLaunchKernelGGL((reservoir_kernel<false, false>), dim3(NBLK), dim3(1024), 0, stream,
                           x, xp, lut, lutp, off, init_res, W, primes, input_nodes, rw, rb, out);
}

// Round 9
// 373.405 us; speedup vs baseline: 1.1483x; 1.0444x over previous
//
#include <hip/hip_runtime.h>
#include <hip/hip_fp16.h>

#define RES 256
#define MS 256
#define ST 512
#define NB 32
#define LUTLEN 262144
#define LUTW 8192      // LUTLEN/32
#define NOUT 32
#define NBLK 256       // 1 sample per block

typedef __attribute__((ext_vector_type(8))) _Float16 half8;
typedef __attribute__((ext_vector_type(4))) float f32x4;

// lgkm-only publish barrier: drain own LDS ops, raw barrier (no vmcnt drain).
__device__ __forceinline__ void publish_barrier() {
    asm volatile("s_waitcnt lgkmcnt(0)" ::: "memory");
    __builtin_amdgcn_s_barrier();
}

// ---- per-node reachable-size + exclusive prefix sum (1 block, 256 thr) ----
__global__ __launch_bounds__(256) void lut_offsets_kernel(const int* __restrict__ W,
                                                          const int* __restrict__ primes,
                                                          int* __restrict__ off) {
    __shared__ int s[RES];
    const int n = threadIdx.x;
    int maxsum = 0;
    for (int k = 0; k < RES; ++k)
        maxsum += (W[n * RES + k] != 0) ? primes[k] : 0;
    int nw = (maxsum >> 5) + 1;
    s[n] = nw;
    __syncthreads();
    for (int d = 1; d < RES; d <<= 1) {
        int v = (n >= d) ? s[n - d] : 0;
        __syncthreads();
        s[n] += v;
        __syncthreads();
    }
    off[n] = s[n] - nw;
    if (n == RES - 1) off[RES] = s[n];
}

// ---- compact bit-pack: block b = node b, words 0..nw-1 ----
__global__ __launch_bounds__(512) void pack_lut2_kernel(const int* __restrict__ lut,
                                                        const int* __restrict__ off,
                                                        unsigned* __restrict__ lutp) {
    const int n = blockIdx.x;
    const int o = off[n];
    const int nw = off[n + 1] - o;
    const int* src = lut + (size_t)n * LUTLEN;
    for (int w = threadIdx.x; w < nw; w += blockDim.x) {
        const int4* p = (const int4*)(src + (size_t)w * 32);
        unsigned word = 0u;
#pragma unroll
        for (int c = 0; c < 8; ++c) {
            const int4 v = p[c];
            word |= (v.x != 0 ? 1u : 0u) << (4 * c + 0);
            word |= (v.y != 0 ? 1u : 0u) << (4 * c + 1);
            word |= (v.z != 0 ? 1u : 0u) << (4 * c + 2);
            word |= (v.w != 0 ? 1u : 0u) << (4 * c + 3);
        }
        lutp[o + w] = word;
    }
}

// Pack x time-major: xp[t*MS + m] = 32 input bits of (m, t).
__global__ __launch_bounds__(256) void pack_x_kernel(const int* __restrict__ x,
                                                     unsigned* __restrict__ xp) {
    const int total = MS * ST;
    int w = blockIdx.x * blockDim.x + threadIdx.x;
    const int stride = gridDim.x * blockDim.x;
    for (; w < total; w += stride) {
        const int4* p = (const int4*)(x + (size_t)w * 32);
        unsigned word = 0u;
#pragma unroll
        for (int c = 0; c < 8; ++c) {
            const int4 v = p[c];
            word |= (v.x != 0 ? 1u : 0u) << (4 * c + 0);
            word |= (v.y != 0 ? 1u : 0u) << (4 * c + 1);
            word |= (v.z != 0 ? 1u : 0u) << (4 * c + 2);
            word |= (v.w != 0 ? 1u : 0u) << (4 * c + 3);
        }
        const int m = w >> 9;
        const int t = w & (ST - 1);
        xp[t * MS + m] = word;
    }
}

// 256 blocks x 512 threads (8 waves = measured optimum); block = 1 sample.
// Broadcast-row A => all 16 C rows identical; lanes 0..31 of each wave each own
// node wid*32+(lane&31): ONE 32-lane gather + ONE contiguous 2B write per wave.
// 16 MFMA/wave as 8 depth-2 chains seeded from a loop-invariant zero C (zc) so
// per-step accumulator zeroing hoists out of the loop. One lgkm-only barrier/step.
template<bool LP, bool XP>
__global__ __launch_bounds__(512) void reservoir_kernel(
    const int* __restrict__ xraw,
    const unsigned* __restrict__ xp,
    const int* __restrict__ lutraw,
    const unsigned* __restrict__ lutp,
    const int* __restrict__ off,
    const int* __restrict__ init_res,
    const int* __restrict__ W,
    const int* __restrict__ primes,
    const int* __restrict__ input_nodes,
    const float* __restrict__ rw,
    const float* __restrict__ rb,
    float* __restrict__ out)
{
    __shared__ __align__(16) _Float16 vArow[2][264];  // double-buffered state row
    __shared__ unsigned xw_lds[ST];                   // this sample's 512 x-words

    const int tid = threadIdx.x;
    const int lane = tid & 63;
    const int wid = tid >> 6;        // 0..7, wave owns nodes wid*32..wid*32+31
    const int g = lane >> 4;         // 0..3 (k-group)
    const int r = lane & 15;         // B col within tile
    const int m0 = blockIdx.x;       // the sample

    const int nn = wid * 32 + (lane & 31);   // this lane's node (valid for lane<32)
    const bool own = (lane < 32);

    const int n0 = wid * 32 + r;     // B-fragment node cols
    const int n1 = n0 + 16;

    const _Float16 pz = (_Float16)(float)primes[nn];
    const _Float16 z  = (_Float16)0.0f;

    const unsigned* lpn = LP ? (lutp + off[nn]) : nullptr;
    int jn = -1;
    for (int j = 0; j < NB; ++j)
        if (input_nodes[j] == nn) jn = j;

    // B fragments (constant): B[k][col] = W[node col][k], 0/1 f16. 64 VGPRs.
    half8 B0[8], B1[8];
#pragma unroll
    for (int kc = 0; kc < 8; ++kc) {
        const int kb = kc * 32 + g * 8;
        const int4* w0p = (const int4*)(W + n0 * RES + kb);
        const int4* w1p = (const int4*)(W + n1 * RES + kb);
        const int4 wa = w0p[0], wb = w0p[1], wc = w1p[0], wd = w1p[1];
        half8 b0, b1;
        b0[0] = wa.x != 0 ? (_Float16)1.0f : z;  b0[1] = wa.y != 0 ? (_Float16)1.0f : z;
        b0[2] = wa.z != 0 ? (_Float16)1.0f : z;  b0[3] = wa.w != 0 ? (_Float16)1.0f : z;
        b0[4] = wb.x != 0 ? (_Float16)1.0f : z;  b0[5] = wb.y != 0 ? (_Float16)1.0f : z;
        b0[6] = wb.z != 0 ? (_Float16)1.0f : z;  b0[7] = wb.w != 0 ? (_Float16)1.0f : z;
        b1[0] = wc.x != 0 ? (_Float16)1.0f : z;  b1[1] = wc.y != 0 ? (_Float16)1.0f : z;
        b1[2] = wc.z != 0 ? (_Float16)1.0f : z;  b1[3] = wc.w != 0 ? (_Float16)1.0f : z;
        b1[4] = wd.x != 0 ? (_Float16)1.0f : z;  b1[5] = wd.y != 0 ? (_Float16)1.0f : z;
        b1[6] = wd.z != 0 ? (_Float16)1.0f : z;  b1[7] = wd.w != 0 ? (_Float16)1.0f : z;
        B0[kc] = b0; B1[kc] = b1;
    }

    // stage this sample's x words into LDS (synced by init barrier)
    if (XP) xw_lds[tid] = xp[tid * MS + m0];

    // init: S(0) = init_res with step-0 scatter
    if (own) {
        int b;
        if (XP) {
            const unsigned x0 = xp[m0];
            b = (jn >= 0) ? (int)((x0 >> jn) & 1u) : (init_res[nn] != 0);
        } else {
            b = (jn >= 0) ? (xraw[(m0 * ST) * NB + jn] != 0) : (init_res[nn] != 0);
        }
        vArow[0][nn] = b ? pz : z;
    }
    __syncthreads();

    // loop-invariant zero C-source: per-step accumulator zeroing hoists out
    const f32x4 zc = {0.f, 0.f, 0.f, 0.f};

    auto STEP = [&](int cur, int nxt, int t) {
        unsigned xa = 0u;
        if (XP) xa = xw_lds[(t + 1) & (ST - 1)];   // wraps at last step; unused then
        half8 A[8];
#pragma unroll
        for (int kc = 0; kc < 8; ++kc)
            A[kc] = *(const half8*)&vArow[cur][kc * 32 + g * 8];  // broadcast read
        // 16 MFMA as 8 independent depth-2 chains seeded from zc
        f32x4 a0 = __builtin_amdgcn_mfma_f32_16x16x32_f16(A[0], B0[0], zc, 0, 0, 0);
        f32x4 b0 = __builtin_amdgcn_mfma_f32_16x16x32_f16(A[0], B1[0], zc, 0, 0, 0);
        f32x4 a1 = __builtin_amdgcn_mfma_f32_16x16x32_f16(A[1], B0[1], zc, 0, 0, 0);
        f32x4 b1 = __builtin_amdgcn_mfma_f32_16x16x32_f16(A[1], B1[1], zc, 0, 0, 0);
        f32x4 a2 = __builtin_amdgcn_mfma_f32_16x16x32_f16(A[2], B0[2], zc, 0, 0, 0);
        f32x4 b2 = __builtin_amdgcn_mfma_f32_16x16x32_f16(A[2], B1[2], zc, 0, 0, 0);
        f32x4 a3 = __builtin_amdgcn_mfma_f32_16x16x32_f16(A[3], B0[3], zc, 0, 0, 0);
        f32x4 b3 = __builtin_amdgcn_mfma_f32_16x16x32_f16(A[3], B1[3], zc, 0, 0, 0);
        a0 = __builtin_amdgcn_mfma_f32_16x16x32_f16(A[4], B0[4], a0, 0, 0, 0);
        b0 = __builtin_amdgcn_mfma_f32_16x16x32_f16(A[4], B1[4], b0, 0, 0, 0);
        a1 = __builtin_amdgcn_mfma_f32_16x16x32_f16(A[5], B0[5], a1, 0, 0, 0);
        b1 = __builtin_amdgcn_mfma_f32_16x16x32_f16(A[5], B1[5], b1, 0, 0, 0);
        a2 = __builtin_amdgcn_mfma_f32_16x16x32_f16(A[6], B0[6], a2, 0, 0, 0);
        b2 = __builtin_amdgcn_mfma_f32_16x16x32_f16(A[6], B1[6], b2, 0, 0, 0);
        a3 = __builtin_amdgcn_mfma_f32_16x16x32_f16(A[7], B0[7], a3, 0, 0, 0);
        b3 = __builtin_amdgcn_mfma_f32_16x16x32_f16(A[7], B1[7], b3, 0, 0, 0);

        if (own) {
            const float fa = (a0[0] + a1[0]) + (a2[0] + a3[0]);
            const float fb = (b0[0] + b1[0]) + (b2[0] + b3[0]);
            const float f = (g == 0) ? fa : fb;   // all C rows identical: g1 holds n1
            const unsigned i = (unsigned)f;
            int b;
            if (LP) {
                const unsigned w = lpn[i >> 5];
                b = (int)((w >> (i & 31u)) & 1u);
            } else {
                b = (lutraw[(size_t)nn * LUTLEN + i] != 0);
            }
            if (t != ST - 1 && jn >= 0) {
                b = XP ? (int)((xa >> jn) & 1u)
                       : (xraw[(m0 * ST + t + 1) * NB + jn] != 0);
            }
            vArow[nxt][nn] = b ? pz : z;          // contiguous 2B x 32 lanes
        }
        publish_barrier();
    };

#pragma unroll 1
    for (int tt = 0; tt < ST; tt += 2) {
        STEP(0, 1, tt);
        STEP(1, 0, tt + 1);
    }

    // readout: final state S(512) in buf 0
    if (tid < NOUT) {
        const int o = tid;
        float acc = rb[o];
        for (int n = 0; n < RES; ++n) {
            if (vArow[0][n] != z) acc += rw[o * RES + n];
        }
        out[m0 * NOUT + o] = acc;
    }
}

extern "C" void kernel_launch(void* const* d_in, const int* in_sizes, int n_in,
                              void* d_out, int out_size, void* d_ws, size_t ws_size,
                              hipStream_t stream) {
    const int* x           = (const int*)d_in[0];
    const int* lut         = (const int*)d_in[1];
    const int* init_res    = (const int*)d_in[2];
    const int* W           = (const int*)d_in[3];
    const int* primes      = (const int*)d_in[4];
    const int* input_nodes = (const int*)d_in[5];
    const float* rw        = (const float*)d_in[6];
    const float* rb        = (const float*)d_in[7];
    float* out = (float*)d_out;

    const size_t lutp_bytes = (size_t)RES * LUTW * sizeof(unsigned); // 8 MB cap
    const size_t xp_bytes   = (size_t)ST * MS * sizeof(unsigned);    // 512 KB
    const size_t off_bytes  = (RES + 1) * sizeof(int);

    unsigned* lutp = nullptr;
    unsigned* xp = nullptr;
    int* off = nullptr;
    bool use_lp = false, use_xp = false;
    unsigned char* ws = (unsigned char*)d_ws;
    if (ws_size >= lutp_bytes + xp_bytes + 256 + off_bytes) {
        lutp = (unsigned*)ws;
        xp = (unsigned*)(ws + lutp_bytes);
        off = (int*)(ws + lutp_bytes + xp_bytes);
        use_lp = use_xp = true;
    } else if (ws_size >= xp_bytes) {
        xp = (unsigned*)ws;
        use_xp = true;
    }

    if (use_lp) {
        hipLaunchKernelGGL(lut_offsets_kernel, dim3(1), dim3(256), 0, stream, W, primes, off);
        hipLaunchKernelGGL(pack_lut2_kernel, dim3(RES), dim3(512), 0, stream, lut, off, lutp);
    }
    if (use_xp) hipLaunchKernelGGL(pack_x_kernel, dim3(512), dim3(256), 0, stream, x, xp);

    if (use_lp)
        hipLaunchKernelGGL((reservoir_kernel<true, true>), dim3(NBLK), dim3(512), 0, stream,
                           x, xp, lut, lutp, off, init_res, W, primes, input_nodes, rw, rb, out);
    else if (use_xp)
        hipLaunchKernelGGL((reservoir_kernel<false, true>), dim3(NBLK), dim3(512), 0, stream,
                           x, xp, lut, lutp, off, init_res, W, primes, input_nodes, rw, rb, out);
    else
        hipLaunchKernelGGL((reservoir_kernel<false, false>), dim3(NBLK), dim3(512), 0, stream,
                           x, xp, lut, lutp, off, init_res, W, primes, input_nodes, rw, rb, out);
}